// Round 8
// baseline (328.969 us; speedup 1.0000x reference)
//
#include <hip/hip_runtime.h>
#include <hip/hip_bf16.h>

#define E_DIM 768
#define H_DIM 64
#define B_SZ 8
#define T_SZ 4096
#define BT (B_SZ * T_SZ)   // 32768

typedef __attribute__((ext_vector_type(8))) short short8;   // 8 bf16 (MFMA A/B frag)
typedef __attribute__((ext_vector_type(4))) float floatx4;  // MFMA C/D frag

// raw barrier: LDS visibility only — does NOT drain vmcnt (prefetch stays in flight)
#define RAWBAR() __asm__ volatile("s_waitcnt lgkmcnt(0)\n\ts_barrier" ::: "memory")

static __device__ __forceinline__ unsigned short bf1(float a) {
    __hip_bfloat16 h = __float2bfloat16(a);
    unsigned short u; __builtin_memcpy(&u, &h, 2); return u;
}
static __device__ __forceinline__ unsigned int pk2(float a, float b) {
    __hip_bfloat162 h = __float22bfloat162_rn(float2{a, b});
    unsigned int u; __builtin_memcpy(&u, &h, 4); return u;
}

// ---------------- W transpose + bf16: Wt[n][k], n = nt*64+nn ----------------
// Wq additionally scaled by log2(e) so attention softmax can use exp2 directly.
__global__ __launch_bounds__(256) void prep_w(
    const float* __restrict__ Wq, const float* __restrict__ Wk,
    const float* __restrict__ Wv, unsigned short* __restrict__ Wt)
{
    __shared__ float Ls[64][65];
    const int nt = blockIdx.x;           // 0..2
    const int kc = blockIdx.y;           // 0..11 (64-k chunk)
    const float* __restrict__ W = (nt == 0) ? Wq : (nt == 1) ? Wk : Wv;
    const float scl = (nt == 0) ? 1.44269504088896f : 1.0f;
    const int t = threadIdx.x;
    const int k0 = kc * 64;

#pragma unroll
    for (int it = 0; it < 16; ++it) {
        const int kk = (t >> 6) + it * 4;
        Ls[kk][t & 63] = W[(size_t)(k0 + kk) * H_DIM + (t & 63)];
    }
    __syncthreads();

#pragma unroll
    for (int it = 0; it < 4; ++it) {
        const int nl = (t >> 4) + it * 16;
        const int kl = (t & 15) * 4;
        unsigned int u[2];
        u[0] = pk2(Ls[kl + 0][nl] * scl, Ls[kl + 1][nl] * scl);
        u[1] = pk2(Ls[kl + 2][nl] * scl, Ls[kl + 3][nl] * scl);
        *(uint2*)(Wt + (size_t)(nt * 64 + nl) * E_DIM + k0 + kl) = *(uint2*)u;
    }
}

// ---------------- projection: W-in-registers, X 2-deep pipelined through 3 LDS buffers ----------------
// grid 256, 768 threads = 12 waves; wave w owns n-tile w (Q:0-3, K:4-7, V:8-11).
// Per m-tile: [LDX(t+2)][STX(t+1)][bar][compute(t)] — single barrier, 2-iteration load slack.
__global__ __launch_bounds__(768, 3) void proj_mfma(
    const float* __restrict__ X, const unsigned short* __restrict__ Wt,
    unsigned short* __restrict__ Qb, unsigned short* __restrict__ Kb,
    unsigned short* __restrict__ Vtb)
{
    __shared__ unsigned short Xs[3][16][776];   // 16-row X tile bf16, 3 buffers

    const int tid  = threadIdx.x;
    const int wave = tid >> 6, lane = tid & 63;
    const int row  = lane & 15, quad = lane >> 4;
    const int m0   = blockIdx.x * 128;

    // W prologue: 24 B-frags resident in registers (96 VGPRs)
    short8 bfr[24];
    {
        const unsigned short* wp = Wt + (size_t)(wave * 16 + row) * E_DIM + quad * 8;
#pragma unroll
        for (int ks = 0; ks < 24; ++ks) bfr[ks] = *(const short8*)(wp + ks * 32);
    }

    // coalesced X staging: consecutive tids cover consecutive 16-float chunks of one row
    const int srow = tid / 48;           // 0..15
    const int sc   = tid % 48;           // 0..47
    const float* __restrict__ xbase = X + (size_t)(m0 + srow) * E_DIM + sc * 16;

    float4 fx[2][4];                     // 2 register slots x 64 B
#define LDX(slot, mt)                                                         \
    {                                                                         \
        const float* p = xbase + (size_t)(mt) * 16 * E_DIM;                   \
        fx[slot][0] = *(const float4*)(p);     fx[slot][1] = *(const float4*)(p + 4);  \
        fx[slot][2] = *(const float4*)(p + 8); fx[slot][3] = *(const float4*)(p + 12); \
    }
#define STX(slot, buf)                                                        \
    {                                                                         \
        unsigned int tmp[8];                                                  \
        tmp[0] = pk2(fx[slot][0].x, fx[slot][0].y); tmp[1] = pk2(fx[slot][0].z, fx[slot][0].w); \
        tmp[2] = pk2(fx[slot][1].x, fx[slot][1].y); tmp[3] = pk2(fx[slot][1].z, fx[slot][1].w); \
        tmp[4] = pk2(fx[slot][2].x, fx[slot][2].y); tmp[5] = pk2(fx[slot][2].z, fx[slot][2].w); \
        tmp[6] = pk2(fx[slot][3].x, fx[slot][3].y); tmp[7] = pk2(fx[slot][3].z, fx[slot][3].w); \
        *(int4*)&Xs[buf][srow][sc * 16]     = *(int4*)&tmp[0];                \
        *(int4*)&Xs[buf][srow][sc * 16 + 8] = *(int4*)&tmp[4];                \
    }

    LDX(0, 0);
    LDX(1, 1);
    STX(0, 0);
    RAWBAR();

    const int g  = wave >> 2;            // 0=Q, 1=K, 2=V
    const int h  = (wave & 3) * 16 + row;
    unsigned short* __restrict__ OQK = (g == 0) ? Qb : Kb;
    const int bb = m0 >> 12;             // batch (block never crosses batch: 128 | 4096)

    int bcur = 0;                        // = mt % 3
    for (int mt = 0; mt < 8; ++mt) {
        if (mt + 2 < 8) LDX(mt & 1, mt + 2);
        if (mt + 1 < 8) {
            int bnext = bcur + 1; if (bnext == 3) bnext = 0;
            STX((mt + 1) & 1, bnext);
        }
        RAWBAR();

        floatx4 acc = (floatx4)0.0f;
#pragma unroll
        for (int ks = 0; ks < 24; ++ks) {
            const short8 af = *(const short8*)&Xs[bcur][row][ks * 32 + quad * 8];
            acc = __builtin_amdgcn_mfma_f32_16x16x32_bf16(af, bfr[ks], acc, 0, 0, 0);
        }

        const int mr = m0 + mt * 16 + quad * 4;
        if (g < 2) {
#pragma unroll
            for (int r = 0; r < 4; ++r)
                OQK[(size_t)(mr + r) * H_DIM + h] = bf1(acc[r]);
        } else {
            const int t0 = mr & 4095;
            unsigned int u[2];
            u[0] = pk2(acc[0], acc[1]); u[1] = pk2(acc[2], acc[3]);
            *(uint2*)(Vtb + ((size_t)bb * H_DIM + h) * T_SZ + t0) = *(uint2*)u;
        }

        ++bcur; if (bcur == 3) bcur = 0;
    }
#undef LDX
#undef STX
}

// ---------------- flash attention: 32-row q-tiles, 4 waves = (q-half x key-half) ----------------
// KV double-buffered in LDS, single RAWBAR per tile, 2-deep register prefetch.
// No-max softmax => split-key partials additive; one LDS combine per block.
__global__ __launch_bounds__(256, 4) void attn_mfma(
    const unsigned short* __restrict__ Qb,
    const unsigned short* __restrict__ Kb,
    const unsigned short* __restrict__ Vtb,
    float* __restrict__ Out)
{
    // KV[buf][0]=K tile [key][h], KV[buf][1]=V^T tile [h][key]; aliased as Oc for the combine
    __shared__ __align__(16) unsigned short KV[2][2][64][72];  // 36864 B
    __shared__ __align__(16) unsigned short Ps[4][16][40];     // per-wave P [q16][key32]
    __shared__ float lc[4][16];

    const int lb   = blockIdx.x;
    const int b    = lb & 7;                   // batch -> XCD (L2 locality)
    const int qq   = 127 - (lb >> 3);          // 32-row q-tile, heavy first (LPT)
    const int tid  = threadIdx.x;
    const int wave = tid >> 6, lane = tid & 63;
    const int col  = lane & 15, quad = lane >> 4;
    const int wq   = wave >> 1;                // q-half (rows wq*16..)
    const int wk   = wave & 1;                 // key-half (keys wk*32..)

    const size_t base = (size_t)b * T_SZ * H_DIM;
    const int q0  = qq * 32;
    const int nkt = (qq >> 1) + 1;             // 64-key tiles needed
    const int ktd = nkt - 1;                   // diagonal tile

    // Q fragments for this wave's 16 q-rows
    short8 qf0, qf1;
    {
        const unsigned short* qp = Qb + base + (size_t)(q0 + wq * 16 + col) * H_DIM + quad * 8;
        qf0 = *(const short8*)(qp);
        qf1 = *(const short8*)(qp + 32);
    }

    floatx4 o[4];
#pragma unroll
    for (int i = 0; i < 4; ++i) o[i] = (floatx4)0.0f;
    float lp[4] = {0.0f, 0.0f, 0.0f, 0.0f};

    // cooperative staging: 32B of K + 32B of V^T per thread per tile
    const int krow = tid >> 2, kcol = (tid & 3) * 16;
    const unsigned short* __restrict__ Ksrc = Kb + base + (size_t)krow * H_DIM + kcol;
    const unsigned short* __restrict__ Vsrc = Vtb + ((size_t)b * H_DIM + krow) * T_SZ + kcol;

    int4 kr[2][2], vr[2][2];                   // 2 register slots
#define LDKV(slot, t)                                                    \
    {                                                                    \
        const unsigned short* kp = Ksrc + (size_t)(t) * 64 * H_DIM;      \
        kr[slot][0] = *(const int4*)kp; kr[slot][1] = *(const int4*)(kp + 8); \
        const unsigned short* vp = Vsrc + (t) * 64;                      \
        vr[slot][0] = *(const int4*)vp; vr[slot][1] = *(const int4*)(vp + 8); \
    }
#define STKV(slot, buf)                                                  \
    {                                                                    \
        *(int4*)&KV[buf][0][krow][kcol]     = kr[slot][0];               \
        *(int4*)&KV[buf][0][krow][kcol + 8] = kr[slot][1];               \
        *(int4*)&KV[buf][1][krow][kcol]     = vr[slot][0];               \
        *(int4*)&KV[buf][1][krow][kcol + 8] = vr[slot][1];               \
    }

    // prologue: tile0 -> buf0 via slot0; tile1 -> slot1 (in flight)
    LDKV(0, 0);
    STKV(0, 0);
    if (nkt > 1) LDKV(1, 1);
    RAWBAR();

    for (int kt = 0; kt < nkt; ++kt) {
        if (kt + 2 < nkt) LDKV(kt & 1, kt + 2);
        if (kt + 1 < nkt) STKV((kt + 1) & 1, (kt + 1) & 1);

        const int buf = kt & 1;

        // S = Q K^T on this wave's 16q x 32k patch (2 key-ntiles)
        floatx4 s[2];
#pragma unroll
        for (int j = 0; j < 2; ++j) {
            const unsigned short* kp = &KV[buf][0][(wk * 2 + j) * 16 + col][quad * 8];
            floatx4 a = (floatx4)0.0f;
            a = __builtin_amdgcn_mfma_f32_16x16x32_bf16(qf0, *(const short8*)(kp),      a, 0, 0, 0);
            a = __builtin_amdgcn_mfma_f32_16x16x32_bf16(qf1, *(const short8*)(kp + 32), a, 0, 0, 0);
            s[j] = a;
        }

        if (kt == ktd) {                       // causal mask on diagonal tile
#pragma unroll
            for (int j = 0; j < 2; ++j) {
                const int keyg = kt * 64 + wk * 32 + j * 16 + col;
#pragma unroll
                for (int r = 0; r < 4; ++r)
                    if (keyg > q0 + wq * 16 + quad * 4 + r) s[j][r] = -1e30f;
            }
        }

        // no-max softmax (Q pre-scaled by log2e): p = exp2(s); no clamp needed (|s| << 127)
#pragma unroll
        for (int r = 0; r < 4; ++r) {
#pragma unroll
            for (int j = 0; j < 2; ++j) {
                const float pv = exp2f(s[j][r]);
                lp[r] += pv;
                Ps[wave][quad * 4 + r][j * 16 + col] = bf1(pv);
            }
        }
        __builtin_amdgcn_wave_barrier();       // per-wave LDS RAW ordering fence

        // O += P V over this wave's 32 keys
        {
            const short8 pa = *(const short8*)(&Ps[wave][col][quad * 8]);
#pragma unroll
            for (int d = 0; d < 4; ++d) {
                const short8 vb = *(const short8*)(&KV[buf][1][d * 16 + col][wk * 32 + quad * 8]);
                o[d] = __builtin_amdgcn_mfma_f32_16x16x32_bf16(pa, vb, o[d], 0, 0, 0);
            }
        }

        RAWBAR();                              // buf free for STKV(kt+2); buf^1 ready for compute(kt+1)
    }

    // l partials: reduce over the 16 col-lanes of each quad group
#pragma unroll
    for (int r = 0; r < 4; ++r) {
        float l = lp[r];
#pragma unroll
        for (int off = 1; off < 16; off <<= 1)
            l += __shfl_xor(l, off, 16);
        if (col == 0) lc[wave][quad * 4 + r] = l;
    }
    __syncthreads();                           // all waves done with KV; lc visible

    // O partials into the KV area (Oc[wave][q16][64])
    float* __restrict__ Oc = (float*)&KV[0][0][0][0];
#pragma unroll
    for (int r = 0; r < 4; ++r)
#pragma unroll
        for (int d = 0; d < 4; ++d)
            Oc[((wave * 16) + quad * 4 + r) * 64 + d * 16 + col] = o[d][r];
    __syncthreads();

    // combine: rows 0-15 <- waves 0+1, rows 16-31 <- waves 2+3
    {
        const int orow = tid >> 3;             // 0..31
        const int d0   = (tid & 7) * 8;        // 0..56
        const int rl   = orow & 15;
        const int wb   = (orow >> 4) * 2;
        const float* p0 = &Oc[((wb * 16) + rl) * 64 + d0];
        const float* p1 = &Oc[(((wb + 1) * 16) + rl) * 64 + d0];
        const float inv = 1.0f / (lc[wb][rl] + lc[wb + 1][rl]);
        float4 a0 = *(const float4*)(p0);
        float4 a1 = *(const float4*)(p0 + 4);
        const float4 b0 = *(const float4*)(p1);
        const float4 b1 = *(const float4*)(p1 + 4);
        a0.x = (a0.x + b0.x) * inv; a0.y = (a0.y + b0.y) * inv;
        a0.z = (a0.z + b0.z) * inv; a0.w = (a0.w + b0.w) * inv;
        a1.x = (a1.x + b1.x) * inv; a1.y = (a1.y + b1.y) * inv;
        a1.z = (a1.z + b1.z) * inv; a1.w = (a1.w + b1.w) * inv;
        float* op = Out + base + (size_t)(q0 + orow) * H_DIM + d0;
        *(float4*)(op)     = a0;
        *(float4*)(op + 4) = a1;
    }
#undef LDKV
#undef STKV
}

extern "C" void kernel_launch(void* const* d_in, const int* in_sizes, int n_in,
                              void* d_out, int out_size, void* d_ws, size_t ws_size,
                              hipStream_t stream) {
    const float* X  = (const float*)d_in[0];
    const float* Wq = (const float*)d_in[1];
    const float* Wk = (const float*)d_in[2];
    const float* Wv = (const float*)d_in[3];

    unsigned short* Wt  = (unsigned short*)d_ws;            // 192*768 bf16
    unsigned short* Qb  = Wt + (size_t)192 * E_DIM;
    unsigned short* Kb  = Qb + (size_t)BT * H_DIM;
    unsigned short* Vtb = Kb + (size_t)BT * H_DIM;          // V transposed [b][h][t]

    prep_w<<<dim3(3, 12), 256, 0, stream>>>(Wq, Wk, Wv, Wt);
    proj_mfma<<<256, 768, 0, stream>>>(X, Wt, Qb, Kb, Vtb);
    attn_mfma<<<1024, 256, 0, stream>>>(Qb, Kb, Vtb, (float*)d_out);
}